// Round 2
// baseline (68687.787 us; speedup 1.0000x reference)
//
#include <hip/hip_runtime.h>
#include <stdint.h>

#define MDIM   1024
#define TSTEPS 8192
#define NWG    256
#define NTHR   256

__device__ __forceinline__ float sigmoidf_(float x) {
  return 1.f / (1.f + __expf(-x));
}

// Poll 4 tagged u64 slots until tag==want, then stage fp32 values into LDS dst.
__device__ __forceinline__ void poll_stage(const unsigned long long* __restrict__ slots,
                                           float* __restrict__ dst, int base, unsigned want) {
  unsigned long long e0, e1, e2, e3;
  for (;;) {
    e0 = __hip_atomic_load(slots + base + 0, __ATOMIC_RELAXED, __HIP_MEMORY_SCOPE_AGENT);
    e1 = __hip_atomic_load(slots + base + 1, __ATOMIC_RELAXED, __HIP_MEMORY_SCOPE_AGENT);
    e2 = __hip_atomic_load(slots + base + 2, __ATOMIC_RELAXED, __HIP_MEMORY_SCOPE_AGENT);
    e3 = __hip_atomic_load(slots + base + 3, __ATOMIC_RELAXED, __HIP_MEMORY_SCOPE_AGENT);
    if ((unsigned)(e0 >> 32) == want && (unsigned)(e1 >> 32) == want &&
        (unsigned)(e2 >> 32) == want && (unsigned)(e3 >> 32) == want) break;
  }
  dst[base + 0] = __uint_as_float((unsigned)e0);
  dst[base + 1] = __uint_as_float((unsigned)e1);
  dst[base + 2] = __uint_as_float((unsigned)e2);
  dst[base + 3] = __uint_as_float((unsigned)e3);
}

__device__ __forceinline__ unsigned long long pack_slot(float v, unsigned tag) {
  return ((unsigned long long)tag << 32) | (unsigned long long)__float_as_uint(v);
}

__global__ __launch_bounds__(NTHR, 1) void ulstm_persistent(
    const float* __restrict__ inputs, const float* __restrict__ Wx,
    const float* __restrict__ bx, const float* __restrict__ Wh,
    const float* __restrict__ bh, const float* __restrict__ Wm,
    const float* __restrict__ bm, float* __restrict__ out,
    unsigned long long* __restrict__ hslot, unsigned long long* __restrict__ vslot)
{
  // LDS: only broadcast buffers; all weights live in fp32 VGPRs.
  __shared__ alignas(16) float xbuf[MDIM];
  __shared__ alignas(16) float hbuf[MDIM];
  __shared__ alignas(16) float vbuf[MDIM];

  const int tid  = threadIdx.x;
  const int wg   = blockIdx.x;
  const int wave = tid >> 6;
  const int lane = tid & 63;
  const int j    = wg * 4 + wave;          // owned column, 0..1023
  const int slotbase = tid * 4;            // 4 slots per thread for staging

  // ---- one-time weight load into registers (fp32) ----
  // wx[g][i*4+s] = Wx[g*M+j][i*256 + lane*4 + s], etc.
  float wx[5][16];
  float wh[4][16];
  float wm[16];
  #pragma unroll
  for (int g = 0; g < 5; ++g) {
    #pragma unroll
    for (int i = 0; i < 4; ++i) {
      const float4 v = *(const float4*)(Wx + ((size_t)(g * MDIM + j)) * MDIM + i * 256 + lane * 4);
      wx[g][i * 4 + 0] = v.x; wx[g][i * 4 + 1] = v.y;
      wx[g][i * 4 + 2] = v.z; wx[g][i * 4 + 3] = v.w;
    }
  }
  #pragma unroll
  for (int g = 0; g < 4; ++g) {
    #pragma unroll
    for (int i = 0; i < 4; ++i) {
      const float4 v = *(const float4*)(Wh + ((size_t)(g * MDIM + j)) * MDIM + i * 256 + lane * 4);
      wh[g][i * 4 + 0] = v.x; wh[g][i * 4 + 1] = v.y;
      wh[g][i * 4 + 2] = v.z; wh[g][i * 4 + 3] = v.w;
    }
  }
  #pragma unroll
  for (int i = 0; i < 4; ++i) {
    const float4 v = *(const float4*)(Wm + (size_t)j * MDIM + i * 256 + lane * 4);
    wm[i * 4 + 0] = v.x; wm[i * 4 + 1] = v.y;
    wm[i * 4 + 2] = v.z; wm[i * 4 + 3] = v.w;
  }

  const float bxi = bx[j],            bxo = bx[MDIM + j],
              bxz = bx[2 * MDIM + j], bxf = bx[3 * MDIM + j],
              bxu = bx[4 * MDIM + j];
  const float bhi = bh[j],            bho = bh[MDIM + j],
              bhz = bh[2 * MDIM + j], bhf = bh[3 * MDIM + j];
  const float bmj = bm[j];

  float c = 0.f, hlast = 0.f;

  for (int t = 0; t < TSTEPS; ++t) {
    // ---- stage inputs[t] (L3-resident after first pass) ----
    {
      float4 v = ((const float4*)(inputs + (size_t)t * MDIM))[tid];
      ((float4*)xbuf)[tid] = v;
    }
    __syncthreads();  // S1

    // ---- x-projections (independent of recurrent state — overlaps with
    //      other WGs finishing the previous step) ----
    float xd[5] = {0, 0, 0, 0, 0};
    #pragma unroll
    for (int i = 0; i < 4; ++i) {
      const float4 xv = *(const float4*)(xbuf + i * 256 + lane * 4);
      #pragma unroll
      for (int g = 0; g < 5; ++g) {
        xd[g] += wx[g][i * 4 + 0] * xv.x + wx[g][i * 4 + 1] * xv.y
               + wx[g][i * 4 + 2] * xv.z + wx[g][i * 4 + 3] * xv.w;
      }
    }
    #pragma unroll
    for (int off = 32; off > 0; off >>= 1) {
      #pragma unroll
      for (int g = 0; g < 5; ++g) xd[g] += __shfl_xor(xd[g], off, 64);
    }

    // ---- wait for h(t-1): tag==t (memset gives tag0/val0 = h(-1)=0) ----
    poll_stage(hslot, hbuf, slotbase, (unsigned)t);
    __syncthreads();  // S2

    // ---- 4 recurrent dots (i,o,z,f rows) from registers ----
    float hd[4] = {0, 0, 0, 0};
    #pragma unroll
    for (int i = 0; i < 4; ++i) {
      const float4 hv = *(const float4*)(hbuf + i * 256 + lane * 4);
      #pragma unroll
      for (int g = 0; g < 4; ++g) {
        hd[g] += wh[g][i * 4 + 0] * hv.x + wh[g][i * 4 + 1] * hv.y
               + wh[g][i * 4 + 2] * hv.z + wh[g][i * 4 + 3] * hv.w;
      }
    }
    #pragma unroll
    for (int off = 32; off > 0; off >>= 1) {
      #pragma unroll
      for (int g = 0; g < 4; ++g) hd[g] += __shfl_xor(hd[g], off, 64);
    }

    const float ig = sigmoidf_(xd[0] + bxi + hd[0] + bhi);
    const float og = sigmoidf_(xd[1] + bxo + hd[1] + bho);
    const float zg = sigmoidf_(xd[2] + bxz + hd[2] + bhz);
    const float fg = sigmoidf_(xd[3] + bxf + hd[3] + bhf);
    const float vj = zg * tanhf(c);
    if (lane == 0) {
      __hip_atomic_store(vslot + j, pack_slot(vj, (unsigned)(t + 1)),
                         __ATOMIC_RELAXED, __HIP_MEMORY_SCOPE_AGENT);
    }

    // ---- wait for v(t): tag==t+1 ----
    poll_stage(vslot, vbuf, slotbase, (unsigned)(t + 1));
    __syncthreads();  // S3

    // ---- Wm row dot from registers ----
    float md = 0;
    #pragma unroll
    for (int i = 0; i < 4; ++i) {
      const float4 vv = *(const float4*)(vbuf + i * 256 + lane * 4);
      md += wm[i * 4 + 0] * vv.x + wm[i * 4 + 1] * vv.y
          + wm[i * 4 + 2] * vv.z + wm[i * 4 + 3] * vv.w;
    }
    #pragma unroll
    for (int off = 32; off > 0; off >>= 1) md += __shfl_xor(md, off, 64);

    const float u = tanhf(xd[4] + bxu + md + bmj);
    c = ig * u + fg * c;
    hlast = og * tanhf(c);
    if (lane == 0) {
      __hip_atomic_store(hslot + j, pack_slot(hlast, (unsigned)(t + 1)),
                         __ATOMIC_RELAXED, __HIP_MEMORY_SCOPE_AGENT);
    }
  }

  if (lane == 0) {
    out[j] = c;              // cT
    out[MDIM + j] = hlast;   // hT
  }
}

extern "C" void kernel_launch(void* const* d_in, const int* in_sizes, int n_in,
                              void* d_out, int out_size, void* d_ws, size_t ws_size,
                              hipStream_t stream) {
  const float* inputs = (const float*)d_in[0];
  const float* Wx     = (const float*)d_in[1];
  const float* bx     = (const float*)d_in[2];
  const float* Wh     = (const float*)d_in[3];
  const float* bh     = (const float*)d_in[4];
  const float* Wm     = (const float*)d_in[5];
  const float* bm     = (const float*)d_in[6];
  float* out = (float*)d_out;

  unsigned long long* hslot = (unsigned long long*)d_ws;
  unsigned long long* vslot = hslot + MDIM;

  // tag 0 / value 0.0f == initial h state; v tag 0 never matches (first want is 1)
  hipMemsetAsync(d_ws, 0, 2 * MDIM * sizeof(unsigned long long), stream);

  ulstm_persistent<<<NWG, NTHR, 0, stream>>>(inputs, Wx, bx, Wh, bh, Wm, bm,
                                             out, hslot, vslot);
}